// Round 15
// baseline (109.264 us; speedup 1.0000x reference)
//
#include <hip/hip_runtime.h>
#include <hip/hip_bf16.h>
#include <cstddef>

namespace {
constexpr int B  = 2;
constexpr int Z  = 200;
constexpr int X  = 200;
constexpr int C  = 128;
constexpr int H  = 4;
constexpr int P  = 8;
constexpr int N  = Z * X;       // 40000
constexpr int BN = B * N;       // 80000
constexpr int SC = 128;         // proj_s cols (f16): [hp][{offx,offy,wp,pad}]
constexpr int NF_P = 14;        // 224/16 output fragments (proj GEMM)
constexpr int NF_O = 8;         // 128/16 output fragments (out GEMM)
constexpr int KS   = 4;         // 128/32 K-steps
constexpr int PLANE = 2200;     // LDS p-plane stride in f16 (4400B: /4 %32 = 12, 16B-aligned)

typedef __attribute__((ext_vector_type(8))) short short8;
typedef __attribute__((ext_vector_type(4))) float f32x4;
typedef _Float16 h16x2 __attribute__((ext_vector_type(2)));

__device__ inline ushort f2bf(float x) {
    __hip_bfloat16 h = __float2bfloat16(x);
    return *reinterpret_cast<ushort*>(&h);
}
__device__ inline unsigned packbf(float a, float b) {
    return (unsigned)f2bf(a) | ((unsigned)f2bf(b) << 16);
}
__device__ inline ushort f2h(float x) {
    _Float16 h = (_Float16)x;
    return __builtin_bit_cast(ushort, h);
}
__device__ inline float h1f(ushort u) {
    return (float)__builtin_bit_cast(_Float16, u);
}
__device__ inline float2 h2f2(unsigned u) {
    h16x2 h = __builtin_bit_cast(h16x2, u);
    return make_float2((float)h[0], (float)h[1]);
}
__device__ inline unsigned packh(float a, float b) {
    return (unsigned)f2h(a) | ((unsigned)f2h(b) << 16);
}
// packed f32->f16x2 convert (v_cvt_pkrtz_f16_f32), bit-cast to our h16x2
__device__ inline h16x2 pkrtz(float a, float b) {
    return __builtin_bit_cast(h16x2, __builtin_amdgcn_cvt_pkrtz(a, b));
}
// single-instruction lane xor-shuffle (BitMode ds_swizzle), within 32-lane groups
template <int MASK>
__device__ inline float swzx(float x) {
    constexpr int pat = (MASK << 10) | 0x1F;
    return __int_as_float(__builtin_amdgcn_ds_swizzle(__float_as_int(x), pat));
}
}

// ---------------------------------------------------------------------------
// W12 = Wout1 @ Wout2 (f32, [129][128]; row 128 = fused bias b12).
// ---------------------------------------------------------------------------
__global__ __launch_bounds__(256) void vsa_k_w12(
    const float* __restrict__ Wout1, const float* __restrict__ bout1,
    const float* __restrict__ Wout2, const float* __restrict__ bout2,
    float* __restrict__ w12)
{
    const int c = threadIdx.x & 127;
    const int k = blockIdx.x * 2 + (threadIdx.x >> 7);
    if (k > 128) return;
    const float* arow = (k < 128) ? (Wout1 + (size_t)k * 128) : bout1;
    float acc = (k < 128) ? 0.f : bout2[c];
    #pragma unroll 4
    for (int j = 0; j < 128; ++j)
        acc = fmaf(arow[j], Wout2[(size_t)j * 128 + c], acc);
    w12[(size_t)k * 128 + c] = acc;
}

// ---------------------------------------------------------------------------
// Prep: pack weights into MFMA fragment order wt[ks][f][lane][8 elems].
// wtp = bf16 (proj GEMM), wtp2 = f16 (out GEMM, from materialized w12).
// ---------------------------------------------------------------------------
__global__ __launch_bounds__(256) void vsa_k_prep(
    const float* __restrict__ Wv,    const float* __restrict__ bv,
    const float* __restrict__ Woff,  const float* __restrict__ boff,
    const float* __restrict__ Wattn, const float* __restrict__ battn,
    const float* __restrict__ w12,
    ushort* __restrict__ wtp, ushort* __restrict__ wtp2,
    float* __restrict__ biasp, float* __restrict__ bias2)
{
    const int u = blockIdx.x * 256 + threadIdx.x;
    constexpr int NP = KS * NF_P * 64;   // 3584
    constexpr int NO = KS * NF_O * 64;   // 2048

    if (u < NP) {
        int ks  = u / (NF_P * 64);
        int rem = u - ks * (NF_P * 64);
        int f = rem >> 6, l = rem & 63;
        int n  = f * 16 + (l & 15);
        int kb = ks * 32 + (l >> 4) * 8;
        float v[8];
        #pragma unroll
        for (int e = 0; e < 8; ++e) {
            int k = kb + e;
            if (n < 128)      v[e] = Wv[k * 128 + n];
            else if (n < 192) v[e] = Woff[k * 64 + (n - 128)];
            else              v[e] = Wattn[k * 32 + (n - 192)];
        }
        unsigned* dst = (unsigned*)(wtp + (size_t)u * 8);
        #pragma unroll
        for (int i = 0; i < 4; ++i) dst[i] = packbf(v[2*i], v[2*i+1]);
    } else if (u < NP + NO) {
        int t   = u - NP;
        int ks  = t / (NF_O * 64);
        int rem = t - ks * (NF_O * 64);
        int f = rem >> 6, l = rem & 63;
        int n  = f * 16 + (l & 15);
        int kb = ks * 32 + (l >> 4) * 8;
        unsigned* dst = (unsigned*)(wtp2 + (size_t)t * 8);
        #pragma unroll
        for (int i = 0; i < 4; ++i)
            dst[i] = packh(w12[(size_t)(kb + 2*i) * 128 + n],
                           w12[(size_t)(kb + 2*i + 1) * 128 + n]);
    } else if (u < NP + NO + 224) {
        int c = u - NP - NO;
        float bb;
        if (c < 128)      bb = bv[c];
        else if (c < 192) bb = boff[c - 128];
        else              bb = battn[c - 192];
        biasp[c] = bb;
    } else if (u < NP + NO + 224 + 128) {
        int c = u - NP - NO - 224;
        bias2[c] = w12[(size_t)128 * 128 + c];
    }
}

// ---------------------------------------------------------------------------
// Fused projection GEMM (MFMA, no LDS) + softmax epilogue, TRANSPOSED-D:
// acc[f] = mfma(Wfrag, Qfrag, acc[f]) -> lane holds q-row (lane&15) and 4
// CONSECUTIVE cols (kg*4..+3 within frag f). Epilogue: wide stores (uint2/
// unsigned) and 1-swizzle softmax (p-halves at lane^16).
// ---------------------------------------------------------------------------
__global__ __launch_bounds__(256) void vsa_k_proj(
    const float* __restrict__ Q, const ushort* __restrict__ wtp,
    const float* __restrict__ biasp,
    ushort* __restrict__ proj_v16, ushort* __restrict__ proj_s16)
{
    const int lane = threadIdx.x & 63;
    const int wave = blockIdx.x * 4 + (threadIdx.x >> 6);
    const int row0 = wave * 16;
    const int m  = lane & 15;
    const int kg = lane >> 4;

    const float* qp = Q + (size_t)(row0 + m) * 128 + kg * 8;

    f32x4 acc[NF_P];
    #pragma unroll
    for (int f = 0; f < NF_P; ++f) acc[f] = (f32x4){0.f, 0.f, 0.f, 0.f};

    #pragma unroll
    for (int ks = 0; ks < KS; ++ks) {
        float4 a0 = *(const float4*)(qp + ks * 32);
        float4 a1 = *(const float4*)(qp + ks * 32 + 4);
        short8 af;
        af[0] = (short)f2bf(a0.x); af[1] = (short)f2bf(a0.y);
        af[2] = (short)f2bf(a0.z); af[3] = (short)f2bf(a0.w);
        af[4] = (short)f2bf(a1.x); af[5] = (short)f2bf(a1.y);
        af[6] = (short)f2bf(a1.z); af[7] = (short)f2bf(a1.w);
        const short8* wrow = (const short8*)wtp + ks * NF_P * 64 + lane;
        #pragma unroll
        for (int f = 0; f < NF_P; ++f)
            acc[f] = __builtin_amdgcn_mfma_f32_16x16x32_bf16(wrow[f * 64], af, acc[f], 0, 0, 0);
    }

    const size_t rb = (size_t)(row0 + m);

    // values -> f16, one uint2 (4 cols) per fragment
    #pragma unroll
    for (int f = 0; f < 8; ++f) {
        const int col0 = f * 16 + kg * 4;
        const float4 bb = *(const float4*)(biasp + col0);
        uint2 o;
        o.x = packh(acc[f][0] + bb.x, acc[f][1] + bb.y);
        o.y = packh(acc[f][2] + bb.z, acc[f][3] + bb.w);
        *(uint2*)(proj_v16 + rb * 128 + col0) = o;
    }
    // offsets -> two {offx,offy} records per fragment
    #pragma unroll
    for (int f = 8; f < 12; ++f) {
        const int col0 = f * 16 + kg * 4;
        const float4 bb = *(const float4*)(biasp + col0);
        const int hp0 = (col0 - 128) >> 1;   // even
        *(unsigned*)(proj_s16 + rb * SC + hp0 * 4)       = packh(acc[f][0] + bb.x, acc[f][1] + bb.y);
        *(unsigned*)(proj_s16 + rb * SC + (hp0 + 1) * 4) = packh(acc[f][2] + bb.z, acc[f][3] + bb.w);
    }
    // attn logits -> softmax (lane holds 4 consecutive p of one h; partner
    // half at lane^16) -> f16 weights at [(h*8+p)*4 + 2]
    #pragma unroll
    for (int f = 12; f < 14; ++f) {
        const int col0 = f * 16 + kg * 4;
        const float4 bb = *(const float4*)(biasp + col0);
        float v0 = acc[f][0] + bb.x, v1 = acc[f][1] + bb.y;
        float v2 = acc[f][2] + bb.z, v3 = acc[f][3] + bb.w;
        float mx = fmaxf(fmaxf(v0, v1), fmaxf(v2, v3));
        mx = fmaxf(mx, swzx<16>(mx));
        const float e0 = __expf(v0 - mx), e1 = __expf(v1 - mx);
        const float e2 = __expf(v2 - mx), e3 = __expf(v3 - mx);
        float sm = e0 + e1 + e2 + e3;
        sm += swzx<16>(sm);
        const float inv = 1.0f / sm;
        const int c0 = col0 - 192;           // h*8 + p of reg 0
        proj_s16[rb * SC + (c0 + 0) * 4 + 2] = f2h(e0 * inv);
        proj_s16[rb * SC + (c0 + 1) * 4 + 2] = f2h(e1 * inv);
        proj_s16[rb * SC + (c0 + 2) * 4 + 2] = f2h(e2 * inv);
        proj_s16[rb * SC + (c0 + 3) * 4 + 2] = f2h(e3 * inv);
    }
}

// ---------------------------------------------------------------------------
// FUSED sampling + output GEMM, NO point-reduce: each (pix,h,p)'s weighted
// bilinear partial goes straight to LDS [p][16][136] (p-plane stride 4400B,
// bank-offset 12). The out GEMM then sums the 8 p-planes via 32 MFMAs
// (f32 accumulate). Transposed-D GEMM: lane holds pix-row (lane&15), 4
// consecutive out cols -> one f32x4 store + f32x4 Q residual.
// XCD swizzle: 5000 blocks = 8 x 625.
// ---------------------------------------------------------------------------
__global__ __launch_bounds__(512) void vsa_k_so(
    const ushort* __restrict__ proj_v16, const ushort* __restrict__ proj_s16,
    const ushort* __restrict__ wtp2, const float* __restrict__ bias2,
    const float* __restrict__ Q, float* __restrict__ out)
{
    __shared__ ushort tmp_lds[P * PLANE];   // 8 planes x (16 x 136 + pad)

    const int lane = threadIdx.x & 63;
    const int wv   = threadIdx.x >> 6;     // wave 0..7
    const int hsub = lane >> 5;            // head within pair
    const int p    = (lane >> 2) & 7;      // point (bits 2..4)
    const int d8   = lane & 3;             // 8-value quad (bits 0..1)

    const int orig = blockIdx.x;                      // 0..4999
    const int wg   = (orig & 7) * 625 + (orig >> 3);  // bijective (5000%8==0)
    const int b    = wg / 2500;
    const int bl0  = (wg - b * 2500) * 16;            // bn_local0, 0..39984
    const int i0   = bl0 / 200;
    const int j0   = bl0 - i0 * 200;
    const int bn0  = b * N + bl0;

    const ushort* vb = proj_v16 + (size_t)b * N * 128;

    // per-unit geometry + upfront offset/weight records
    int pix_t[4], h_t[4];
    float fi_t[4], fj_t[4];
    uint2 ow[4];
    #pragma unroll
    for (int t = 0; t < 4; ++t) {
        const int unit = t * 8 + wv;        // 0..31
        const int pix  = unit >> 1;
        pix_t[t] = pix;
        h_t[t]   = (unit & 1) * 2 + hsub;
        const int jr   = j0 + pix;
        const bool wr  = jr >= 200;
        fi_t[t] = (float)(i0 + (wr ? 1 : 0));
        fj_t[t] = (float)(wr ? jr - 200 : jr);
        ow[t] = *(const uint2*)(proj_s16 + (size_t)(bn0 + pix) * SC + (h_t[t] * 8 + p) * 4);
    }

    #pragma unroll
    for (int t = 0; t < 4; ++t) {
        const float2 off = h2f2(ow[t].x);
        const float  wp  = h1f((ushort)(ow[t].y & 0xffff));

        const float ixf = fi_t[t] + off.x;
        const float iyf = fj_t[t] + off.y;
        const float x0f = floorf(ixf), y0f = floorf(iyf);
        const float lx = ixf - x0f, ly = iyf - y0f;
        const int x0 = (int)x0f, y0 = (int)y0f;
        const int x1 = x0 + 1,  y1 = y0 + 1;
        const int xc0 = min(max(x0, 0), X - 1), xc1 = min(max(x1, 0), X - 1);
        const int yc0 = min(max(y0, 0), Z - 1), yc1 = min(max(y1, 0), Z - 1);

        const float wx0 = ((unsigned)x0 < (unsigned)X) ? (1.f - lx) : 0.f;
        const float wx1 = ((unsigned)x1 < (unsigned)X) ? lx : 0.f;
        const float wy0 = (((unsigned)y0 < (unsigned)Z) ? (1.f - ly) : 0.f) * wp;
        const float wy1 = (((unsigned)y1 < (unsigned)Z) ? ly : 0.f) * wp;

        const h16x2 w00p = pkrtz(wx0 * wy0, wx0 * wy0);
        const h16x2 w10p = pkrtz(wx1 * wy0, wx1 * wy0);
        const h16x2 w01p = pkrtz(wx0 * wy1, wx0 * wy1);
        const h16x2 w11p = pkrtz(wx1 * wy1, wx1 * wy1);

        const int rb0 = yc0 * X, rb1 = yc1 * X;
        const int hb  = h_t[t] * 32 + d8 * 8;

        const uint4 c00 = *(const uint4*)(vb + (size_t)(rb0 + xc0) * 128 + hb);
        const uint4 c10 = *(const uint4*)(vb + (size_t)(rb0 + xc1) * 128 + hb);
        const uint4 c01 = *(const uint4*)(vb + (size_t)(rb1 + xc0) * 128 + hb);
        const uint4 c11 = *(const uint4*)(vb + (size_t)(rb1 + xc1) * 128 + hb);

        h16x2 a0 = (h16x2)0, a1 = (h16x2)0, a2 = (h16x2)0, a3 = (h16x2)0;
        #define VSA_ACC(c, wpk) { \
            a0 = __builtin_elementwise_fma(__builtin_bit_cast(h16x2, (c).x), wpk, a0); \
            a1 = __builtin_elementwise_fma(__builtin_bit_cast(h16x2, (c).y), wpk, a1); \
            a2 = __builtin_elementwise_fma(__builtin_bit_cast(h16x2, (c).z), wpk, a2); \
            a3 = __builtin_elementwise_fma(__builtin_bit_cast(h16x2, (c).w), wpk, a3); }
        VSA_ACC(c00, w00p)
        VSA_ACC(c10, w10p)
        VSA_ACC(c01, w01p)
        VSA_ACC(c11, w11p)
        #undef VSA_ACC

        // per-point partial straight to LDS (no reduce): plane p
        uint4 o;
        o.x = __builtin_bit_cast(unsigned, a0);
        o.y = __builtin_bit_cast(unsigned, a1);
        o.z = __builtin_bit_cast(unsigned, a2);
        o.w = __builtin_bit_cast(unsigned, a3);
        *(uint4*)(&tmp_lds[p * PLANE + pix_t[t] * 136 + h_t[t] * 32 + d8 * 8]) = o;
    }

    // ---- prefetch Q residual (transposed rows: lane&15 = pix row) ----
    const int m   = lane & 15;
    const int kg  = lane >> 4;
    const int col0 = wv * 16 + kg * 4;
    const f32x4 qv = __builtin_nontemporal_load(
        (const f32x4*)(Q + (size_t)(bn0 + m) * 128 + col0));

    __syncthreads();

    // ---- output GEMM: acc = sum over ks, p of mfma(Wfrag, A_p frag) ----
    f32x4 acc = (f32x4){0.f, 0.f, 0.f, 0.f};
    #pragma unroll
    for (int ks = 0; ks < KS; ++ks) {
        const short8 wfrag = ((const short8*)wtp2)[ks * NF_O * 64 + wv * 64 + lane];
        #pragma unroll
        for (int pp = 0; pp < P; ++pp) {
            const short8 af = *(const short8*)(&tmp_lds[pp * PLANE + m * 136 + ks * 32 + kg * 8]);
            acc = __builtin_amdgcn_mfma_f32_16x16x32_f16(wfrag, af, acc, 0, 0, 0);
        }
    }

    const f32x4 bb = *(const f32x4*)(bias2 + col0);
    f32x4 o = acc + bb + qv;
    __builtin_nontemporal_store(o, (f32x4*)(out + (size_t)(bn0 + m) * 128 + col0));
}

// ---------------------------------------------------------------------------
extern "C" void kernel_launch(void* const* d_in, const int* in_sizes, int n_in,
                              void* d_out, int out_size, void* d_ws, size_t ws_size,
                              hipStream_t stream) {
    const float* Q     = (const float*)d_in[0];
    const float* Wv    = (const float*)d_in[1];
    const float* bv    = (const float*)d_in[2];
    const float* Woff  = (const float*)d_in[3];
    const float* boff  = (const float*)d_in[4];
    const float* Wattn = (const float*)d_in[5];
    const float* battn = (const float*)d_in[6];
    const float* Wout1 = (const float*)d_in[7];
    const float* bout1 = (const float*)d_in[8];
    const float* Wout2 = (const float*)d_in[9];
    const float* bout2 = (const float*)d_in[10];
    float* out = (float*)d_out;

    // Workspace: biasp f32[224] | b12 f32[128] | w12 f32[129*128] |
    //            proj_s16 u16[BN][128] | proj_v16 u16[BN][128] | wtp | wtp2
    float*  biasp  = (float*)d_ws;
    float*  bias2  = biasp + 224;
    float*  w12    = bias2 + 128;
    ushort* proj_s16 = (ushort*)(w12 + 129 * 128);
    ushort* proj_v16 = proj_s16 + (size_t)BN * SC;
    ushort* wtp    = proj_v16 + (size_t)BN * 128;
    ushort* wtp2   = wtp + (size_t)KS * NF_P * 64 * 8;

    constexpr int prep_n = KS * NF_P * 64 + KS * NF_O * 64 + 224 + 128; // 5984
    vsa_k_w12<<<65, 256, 0, stream>>>(Wout1, bout1, Wout2, bout2, w12);
    vsa_k_prep<<<(prep_n + 255) / 256, 256, 0, stream>>>(
        Wv, bv, Woff, boff, Wattn, battn, w12, wtp, wtp2, biasp, bias2);
    vsa_k_proj<<<BN / 64, 256, 0, stream>>>(Q, wtp, biasp, proj_v16, proj_s16);
    vsa_k_so<<<BN / 16, 512, 0, stream>>>(proj_v16, proj_s16, wtp2, bias2, Q, out);
}

// Round 16
// 101.186 us; speedup vs baseline: 1.0798x; 1.0798x over previous
//
#include <hip/hip_runtime.h>
#include <hip/hip_bf16.h>
#include <cstddef>

namespace {
constexpr int B  = 2;
constexpr int Z  = 200;
constexpr int X  = 200;
constexpr int C  = 128;
constexpr int H  = 4;
constexpr int P  = 8;
constexpr int N  = Z * X;       // 40000
constexpr int BN = B * N;       // 80000
constexpr int SC = 128;         // proj_s cols (f16): [hp][{offx,offy,wp,pad}]
constexpr int NF_P = 14;        // 224/16 output fragments (proj GEMM)
constexpr int NF_O = 8;         // 128/16 output fragments (out GEMM)
constexpr int KS   = 4;         // 128/32 K-steps
// Padded value image: 248 rows x 256 cols of 128-f16 pixels, border 24.
constexpr int PW   = 256;       // padded width (px)
constexpr int PH   = 248;       // padded height (px)
constexpr int BORD = 24;
constexpr size_t VB_STRIDE = (size_t)PH * PW * 128;   // f16 elems per batch

typedef __attribute__((ext_vector_type(8))) short short8;
typedef __attribute__((ext_vector_type(4))) float f32x4;
typedef _Float16 h16x2 __attribute__((ext_vector_type(2)));

__device__ inline ushort f2bf(float x) {
    __hip_bfloat16 h = __float2bfloat16(x);
    return *reinterpret_cast<ushort*>(&h);
}
__device__ inline unsigned packbf(float a, float b) {
    return (unsigned)f2bf(a) | ((unsigned)f2bf(b) << 16);
}
__device__ inline ushort f2h(float x) {
    _Float16 h = (_Float16)x;
    return __builtin_bit_cast(ushort, h);
}
__device__ inline float h1f(ushort u) {
    return (float)__builtin_bit_cast(_Float16, u);
}
__device__ inline float2 h2f2(unsigned u) {
    h16x2 h = __builtin_bit_cast(h16x2, u);
    return make_float2((float)h[0], (float)h[1]);
}
__device__ inline unsigned packh(float a, float b) {
    return (unsigned)f2h(a) | ((unsigned)f2h(b) << 16);
}
// packed f32->f16x2 convert (v_cvt_pkrtz_f16_f32), bit-cast to our h16x2
__device__ inline h16x2 pkrtz(float a, float b) {
    return __builtin_bit_cast(h16x2, __builtin_amdgcn_cvt_pkrtz(a, b));
}
// single-instruction lane xor-shuffles (BitMode ds_swizzle), within 32-lane groups
template <int MASK>
__device__ inline float swzx(float x) {
    constexpr int pat = (MASK << 10) | 0x1F;
    return __int_as_float(__builtin_amdgcn_ds_swizzle(__float_as_int(x), pat));
}
template <int MASK>
__device__ inline h16x2 swzh(h16x2 x) {
    constexpr int pat = (MASK << 10) | 0x1F;
    int t = __builtin_amdgcn_ds_swizzle(__builtin_bit_cast(int, x), pat);
    return __builtin_bit_cast(h16x2, t);
}
}

// ---------------------------------------------------------------------------
// W12 = Wout1 @ Wout2 (blocks 0..64) + zero the padded-image border
// (blocks 65..560: one block per (batch, padded row)).
// ---------------------------------------------------------------------------
__global__ __launch_bounds__(256) void vsa_k_w12b(
    const float* __restrict__ Wout1, const float* __restrict__ bout1,
    const float* __restrict__ Wout2, const float* __restrict__ bout2,
    float* __restrict__ w12, ushort* __restrict__ proj_vp)
{
    if (blockIdx.x >= 65) {
        const int bid2 = blockIdx.x - 65;          // 0..495
        const int bb = bid2 / PH, Y = bid2 - bb * PH;
        const bool borderRow = (Y < BORD) || (Y >= PH - BORD);
        int px = -1;
        if (borderRow) px = threadIdx.x;           // all 256 px
        else if (threadIdx.x < 2 * BORD)
            px = (threadIdx.x < BORD) ? (int)threadIdx.x : (int)threadIdx.x + (PW - 2 * BORD);
        if (px >= 0) {
            uint4* dst = (uint4*)(proj_vp + (size_t)bb * VB_STRIDE + ((size_t)Y * PW + px) * 128);
            const uint4 z = {0u, 0u, 0u, 0u};
            #pragma unroll
            for (int q = 0; q < 16; ++q) dst[q] = z;
        }
        return;
    }
    const int c = threadIdx.x & 127;
    const int k = blockIdx.x * 2 + (threadIdx.x >> 7);
    if (k > 128) return;
    const float* arow = (k < 128) ? (Wout1 + (size_t)k * 128) : bout1;
    float acc = (k < 128) ? 0.f : bout2[c];
    #pragma unroll 4
    for (int j = 0; j < 128; ++j)
        acc = fmaf(arow[j], Wout2[(size_t)j * 128 + c], acc);
    w12[(size_t)k * 128 + c] = acc;
}

// ---------------------------------------------------------------------------
// Prep: pack weights into MFMA fragment order wt[ks][f][lane][8 elems].
// wtp = bf16 (proj GEMM), wtp2 = f16 (out GEMM, from materialized w12).
// ---------------------------------------------------------------------------
__global__ __launch_bounds__(256) void vsa_k_prep(
    const float* __restrict__ Wv,    const float* __restrict__ bv,
    const float* __restrict__ Woff,  const float* __restrict__ boff,
    const float* __restrict__ Wattn, const float* __restrict__ battn,
    const float* __restrict__ w12,
    ushort* __restrict__ wtp, ushort* __restrict__ wtp2,
    float* __restrict__ biasp, float* __restrict__ bias2)
{
    const int u = blockIdx.x * 256 + threadIdx.x;
    constexpr int NP = KS * NF_P * 64;   // 3584
    constexpr int NO = KS * NF_O * 64;   // 2048

    if (u < NP) {
        int ks  = u / (NF_P * 64);
        int rem = u - ks * (NF_P * 64);
        int f = rem >> 6, l = rem & 63;
        int n  = f * 16 + (l & 15);
        int kb = ks * 32 + (l >> 4) * 8;
        float v[8];
        #pragma unroll
        for (int e = 0; e < 8; ++e) {
            int k = kb + e;
            if (n < 128)      v[e] = Wv[k * 128 + n];
            else if (n < 192) v[e] = Woff[k * 64 + (n - 128)];
            else              v[e] = Wattn[k * 32 + (n - 192)];
        }
        unsigned* dst = (unsigned*)(wtp + (size_t)u * 8);
        #pragma unroll
        for (int i = 0; i < 4; ++i) dst[i] = packbf(v[2*i], v[2*i+1]);
    } else if (u < NP + NO) {
        int t   = u - NP;
        int ks  = t / (NF_O * 64);
        int rem = t - ks * (NF_O * 64);
        int f = rem >> 6, l = rem & 63;
        int n  = f * 16 + (l & 15);
        int kb = ks * 32 + (l >> 4) * 8;
        unsigned* dst = (unsigned*)(wtp2 + (size_t)t * 8);
        #pragma unroll
        for (int i = 0; i < 4; ++i)
            dst[i] = packh(w12[(size_t)(kb + 2*i) * 128 + n],
                           w12[(size_t)(kb + 2*i + 1) * 128 + n]);
    } else if (u < NP + NO + 224) {
        int c = u - NP - NO;
        float bb;
        if (c < 128)      bb = bv[c];
        else if (c < 192) bb = boff[c - 128];
        else              bb = battn[c - 192];
        biasp[c] = bb;
    } else if (u < NP + NO + 224 + 128) {
        int c = u - NP - NO - 224;
        bias2[c] = w12[(size_t)128 * 128 + c];
    }
}

// ---------------------------------------------------------------------------
// Fused projection GEMM (MFMA, no LDS) + softmax epilogue (r12 layout).
//   cols 0..127   -> proj_vp (f16 values, PADDED image layout)
//   cols 128..191 -> proj_s16[row][hp*4 + {0,1}] (f16 offsets)
//   cols 192..223 -> softmax over 8-point groups -> proj_s16[row][hp*4+2]
// ---------------------------------------------------------------------------
__global__ __launch_bounds__(256) void vsa_k_proj(
    const float* __restrict__ Q, const ushort* __restrict__ wtp,
    const float* __restrict__ biasp,
    ushort* __restrict__ proj_vp, ushort* __restrict__ proj_s16)
{
    const int lane = threadIdx.x & 63;
    const int wave = blockIdx.x * 4 + (threadIdx.x >> 6);
    const int row0 = wave * 16;
    const int m  = lane & 15;
    const int kg = lane >> 4;

    const float* qp = Q + (size_t)(row0 + m) * 128 + kg * 8;

    f32x4 acc[NF_P];
    #pragma unroll
    for (int f = 0; f < NF_P; ++f) acc[f] = (f32x4){0.f, 0.f, 0.f, 0.f};

    #pragma unroll
    for (int ks = 0; ks < KS; ++ks) {
        float4 a0 = *(const float4*)(qp + ks * 32);
        float4 a1 = *(const float4*)(qp + ks * 32 + 4);
        short8 af;
        af[0] = (short)f2bf(a0.x); af[1] = (short)f2bf(a0.y);
        af[2] = (short)f2bf(a0.z); af[3] = (short)f2bf(a0.w);
        af[4] = (short)f2bf(a1.x); af[5] = (short)f2bf(a1.y);
        af[6] = (short)f2bf(a1.z); af[7] = (short)f2bf(a1.w);
        const short8* wrow = (const short8*)wtp + ks * NF_P * 64 + lane;
        #pragma unroll
        for (int f = 0; f < NF_P; ++f)
            acc[f] = __builtin_amdgcn_mfma_f32_16x16x32_bf16(af, wrow[f * 64], acc[f], 0, 0, 0);
    }

    // padded row addresses for the 4 rows this lane writes (value pixels)
    const int bb  = row0 / 40000;
    const int lcl = row0 - bb * 40000;
    const int y0p = lcl / 200;
    const int x0p = lcl - y0p * 200;
    size_t prow[4];
    #pragma unroll
    for (int r = 0; r < 4; ++r) {
        const int idx = kg * 4 + r;
        int xr = x0p + idx, yr = y0p;
        if (xr >= 200) { xr -= 200; yr += 1; }
        prow[r] = (size_t)bb * VB_STRIDE + (((size_t)(yr + BORD) * PW) + (xr + BORD)) * 128;
    }

    // values -> f16 into padded image
    #pragma unroll
    for (int f = 0; f < 8; ++f) {
        const int col = f * 16 + m;
        const float bbv = biasp[col];
        #pragma unroll
        for (int r = 0; r < 4; ++r)
            proj_vp[prow[r] + col] = f2h(acc[f][r] + bbv);
    }
    // offsets -> f16 at [hp*4 + comp]
    #pragma unroll
    for (int f = 8; f < 12; ++f) {
        const int col = f * 16 + m;
        const float bbv = biasp[col];
        const int c  = col - 128;          // 0..63
        const int hp = c >> 1, comp = c & 1;
        #pragma unroll
        for (int r = 0; r < 4; ++r)
            proj_s16[(size_t)(row0 + kg * 4 + r) * SC + hp * 4 + comp] = f2h(acc[f][r] + bbv);
    }
    // attn logits -> softmax -> f16 weights at [hp*4 + 2]
    #pragma unroll
    for (int f = 12; f < 14; ++f) {
        const float bbv = biasp[f * 16 + m];
        const int hp = (f - 12) * 16 + m;  // 0..31
        #pragma unroll
        for (int r = 0; r < 4; ++r) {
            float v = acc[f][r] + bbv;
            float mx = v;
            mx = fmaxf(mx, swzx<1>(mx));
            mx = fmaxf(mx, swzx<2>(mx));
            mx = fmaxf(mx, swzx<4>(mx));
            float ex = __expf(v - mx);
            float sm = ex;
            sm += swzx<1>(sm); sm += swzx<2>(sm); sm += swzx<4>(sm);
            const float wp = ex / sm;
            proj_s16[(size_t)(row0 + kg * 4 + r) * SC + hp * 4 + 2] = f2h(wp);
        }
    }
}

// ---------------------------------------------------------------------------
// FUSED sampling + output GEMM (r12 structure, PADDED gather):
// 8 waves/block, 4 units/wave. Zero border + point clamp replace all bounds
// logic; corner addrs = shift-built base + {0, 256B, 64KiB, 64KiB+256B}.
// Reduce = ds_swizzle xor 4/8/16; LDS tile; 1 fragment/wave f16 MFMA;
// nontemporal Q/out. XCD swizzle: 5000 blocks = 8 x 625.
// ---------------------------------------------------------------------------
__global__ __launch_bounds__(512) void vsa_k_so(
    const ushort* __restrict__ proj_vp, const ushort* __restrict__ proj_s16,
    const ushort* __restrict__ wtp2, const float* __restrict__ bias2,
    const float* __restrict__ Q, float* __restrict__ out)
{
    __shared__ ushort tmp_lds[16][136];   // 16 rows x 128 f16, pad 8 (16B)

    const int lane = threadIdx.x & 63;
    const int wv   = threadIdx.x >> 6;     // wave 0..7
    const int hsub = lane >> 5;            // head within pair
    const int p    = (lane >> 2) & 7;      // point (bits 2..4)
    const int d8   = lane & 3;             // 8-value quad (bits 0..1)
    const int h    = (wv & 1) * 2 + hsub;  // wave-constant head
    const int hb   = h * 64 + d8 * 16;     // byte offset within 256B pixel

    const int orig = blockIdx.x;                      // 0..4999
    const int wg   = (orig & 7) * 625 + (orig >> 3);  // bijective (5000%8==0)
    const int b    = wg / 2500;
    const int bl0  = (wg - b * 2500) * 16;            // bn_local0, 0..39984
    const int i0   = bl0 / 200;
    const int j0   = bl0 - i0 * 200;
    const int bn0  = b * N + bl0;

    const char* vbp = (const char*)(proj_vp + (size_t)b * VB_STRIDE);

    #pragma unroll
    for (int t = 0; t < 4; ++t) {
        const int pix  = t * 4 + (wv >> 1);  // unit>>1, unit = t*8+wv
        const int jr   = j0 + pix;
        const bool wr  = jr >= 200;          // 16 consecutive bn may wrap one i
        const float fi = (float)(i0 + (wr ? 1 : 0));
        const float fj = (float)(wr ? jr - 200 : jr);
        const int bn   = bn0 + pix;

        // per-point data: one uint2 = {offx, offy, wp, pad} f16
        const uint2 ow = *(const uint2*)(proj_s16 + (size_t)bn * SC + (h * 8 + p) * 4);
        const float2 off = h2f2(ow.x);
        const float  wp  = h1f((ushort)(ow.y & 0xffff));

        // clamp into the zero-border region (exact zero-pad semantics)
        const float ixf = fminf(fmaxf(fi + off.x, -23.f), 222.f);
        const float iyf = fminf(fmaxf(fj + off.y, -23.f), 222.f);
        const float x0f = floorf(ixf), y0f = floorf(iyf);
        const float lx = ixf - x0f, ly = iyf - y0f;
        const int Xp = (int)x0f + BORD;     // 1..246
        const int Yp = (int)y0f + BORD;     // 1..246

        const float wy0 = (1.f - ly) * wp;
        const float wy1 = ly * wp;
        const h16x2 w00p = pkrtz((1.f - lx) * wy0, (1.f - lx) * wy0);
        const h16x2 w10p = pkrtz(lx * wy0, lx * wy0);
        const h16x2 w01p = pkrtz((1.f - lx) * wy1, (1.f - lx) * wy1);
        const h16x2 w11p = pkrtz(lx * wy1, lx * wy1);

        // corner addresses: one base, x+1 = +256B, y+1 = +65536B
        const char* base = vbp + ((((size_t)Yp << 8) + Xp) << 8) + hb;
        const uint4 c00 = *(const uint4*)(base);
        const uint4 c10 = *(const uint4*)(base + 256);
        const uint4 c01 = *(const uint4*)(base + 65536);
        const uint4 c11 = *(const uint4*)(base + 65536 + 256);

        h16x2 a0 = (h16x2)0, a1 = (h16x2)0, a2 = (h16x2)0, a3 = (h16x2)0;
        #define VSA_ACC(c, wpk) { \
            a0 = __builtin_elementwise_fma(__builtin_bit_cast(h16x2, (c).x), wpk, a0); \
            a1 = __builtin_elementwise_fma(__builtin_bit_cast(h16x2, (c).y), wpk, a1); \
            a2 = __builtin_elementwise_fma(__builtin_bit_cast(h16x2, (c).z), wpk, a2); \
            a3 = __builtin_elementwise_fma(__builtin_bit_cast(h16x2, (c).w), wpk, a3); }
        VSA_ACC(c00, w00p)
        VSA_ACC(c10, w10p)
        VSA_ACC(c01, w01p)
        VSA_ACC(c11, w11p)
        #undef VSA_ACC

        // reduce over the 8 points (p = lane bits 2..4), within 32 lanes
        a0 += swzh<4>(a0);  a1 += swzh<4>(a1);  a2 += swzh<4>(a2);  a3 += swzh<4>(a3);
        a0 += swzh<8>(a0);  a1 += swzh<8>(a1);  a2 += swzh<8>(a2);  a3 += swzh<8>(a3);
        a0 += swzh<16>(a0); a1 += swzh<16>(a1); a2 += swzh<16>(a2); a3 += swzh<16>(a3);

        if (p == 0) {   // lanes {0..3, 32..35}: one 16B LDS store per head
            uint4 o;
            o.x = __builtin_bit_cast(unsigned, a0);
            o.y = __builtin_bit_cast(unsigned, a1);
            o.z = __builtin_bit_cast(unsigned, a2);
            o.w = __builtin_bit_cast(unsigned, a3);
            *(uint4*)(&tmp_lds[pix][h * 32 + d8 * 8]) = o;
        }
    }

    // ---- prefetch Q residual (hides under barrier + GEMM) ----
    const int m  = lane & 15;
    const int kg = lane >> 4;
    const int col = wv * 16 + m;
    float qv[4];
    #pragma unroll
    for (int r = 0; r < 4; ++r)
        qv[r] = __builtin_nontemporal_load(Q + (size_t)(bn0 + kg * 4 + r) * 128 + col);

    __syncthreads();

    // ---- output GEMM phase: wave wv owns fragment wv ----
    f32x4 acc = (f32x4){0.f, 0.f, 0.f, 0.f};
    #pragma unroll
    for (int ks = 0; ks < KS; ++ks) {
        short8 af = *(const short8*)(&tmp_lds[m][ks * 32 + kg * 8]);
        const short8* wrow = (const short8*)wtp2 + ks * NF_O * 64 + lane;
        acc = __builtin_amdgcn_mfma_f32_16x16x32_f16(af, wrow[wv * 64], acc, 0, 0, 0);
    }

    const float bb = bias2[col];
    #pragma unroll
    for (int r = 0; r < 4; ++r) {
        const size_t gi = (size_t)(bn0 + kg * 4 + r) * 128 + col;
        __builtin_nontemporal_store(acc[r] + bb + qv[r], out + gi);
    }
}

// ---------------------------------------------------------------------------
extern "C" void kernel_launch(void* const* d_in, const int* in_sizes, int n_in,
                              void* d_out, int out_size, void* d_ws, size_t ws_size,
                              hipStream_t stream) {
    const float* Q     = (const float*)d_in[0];
    const float* Wv    = (const float*)d_in[1];
    const float* bv    = (const float*)d_in[2];
    const float* Woff  = (const float*)d_in[3];
    const float* boff  = (const float*)d_in[4];
    const float* Wattn = (const float*)d_in[5];
    const float* battn = (const float*)d_in[6];
    const float* Wout1 = (const float*)d_in[7];
    const float* bout1 = (const float*)d_in[8];
    const float* Wout2 = (const float*)d_in[9];
    const float* bout2 = (const float*)d_in[10];
    float* out = (float*)d_out;

    // Workspace: biasp f32[224] | b12 f32[128] | w12 f32[129*128] |
    //            proj_s16 u16[BN][128] | proj_vp u16[2][248*256*128] | wtp | wtp2
    float*  biasp  = (float*)d_ws;
    float*  bias2  = biasp + 224;
    float*  w12    = bias2 + 128;
    ushort* proj_s16 = (ushort*)(w12 + 129 * 128);
    ushort* proj_vp  = proj_s16 + (size_t)BN * SC;
    ushort* wtp    = proj_vp + 2 * VB_STRIDE;
    ushort* wtp2   = wtp + (size_t)KS * NF_P * 64 * 8;

    constexpr int prep_n = KS * NF_P * 64 + KS * NF_O * 64 + 224 + 128; // 5984
    vsa_k_w12b<<<65 + 2 * PH, 256, 0, stream>>>(Wout1, bout1, Wout2, bout2, w12, proj_vp);
    vsa_k_prep<<<(prep_n + 255) / 256, 256, 0, stream>>>(
        Wv, bv, Woff, boff, Wattn, battn, w12, wtp, wtp2, biasp, bias2);
    vsa_k_proj<<<BN / 64, 256, 0, stream>>>(Q, wtp, biasp, proj_vp, proj_s16);
    vsa_k_so<<<BN / 16, 512, 0, stream>>>(proj_vp, proj_s16, wtp2, bias2, Q, out);
}

// Round 17
// 90.423 us; speedup vs baseline: 1.2084x; 1.1190x over previous
//
#include <hip/hip_runtime.h>
#include <hip/hip_bf16.h>
#include <cstddef>

namespace {
constexpr int B  = 2;
constexpr int Z  = 200;
constexpr int X  = 200;
constexpr int C  = 128;
constexpr int H  = 4;
constexpr int P  = 8;
constexpr int N  = Z * X;       // 40000
constexpr int BN = B * N;       // 80000
constexpr int SC = 128;         // proj_s cols (f16): [hp][{offx,offy,wp,pad}]
constexpr int NF_P = 14;        // 224/16 output fragments (proj GEMM)
constexpr int NF_O = 8;         // 128/16 output fragments (out GEMM)
constexpr int KS   = 4;         // 128/32 K-steps

typedef __attribute__((ext_vector_type(8))) short short8;
typedef __attribute__((ext_vector_type(4))) float f32x4;
typedef _Float16 h16x2 __attribute__((ext_vector_type(2)));

__device__ inline ushort f2bf(float x) {
    __hip_bfloat16 h = __float2bfloat16(x);
    return *reinterpret_cast<ushort*>(&h);
}
__device__ inline unsigned packbf(float a, float b) {
    return (unsigned)f2bf(a) | ((unsigned)f2bf(b) << 16);
}
__device__ inline ushort f2h(float x) {
    _Float16 h = (_Float16)x;
    return __builtin_bit_cast(ushort, h);
}
__device__ inline float h1f(ushort u) {
    return (float)__builtin_bit_cast(_Float16, u);
}
__device__ inline float2 h2f2(unsigned u) {
    h16x2 h = __builtin_bit_cast(h16x2, u);
    return make_float2((float)h[0], (float)h[1]);
}
__device__ inline unsigned packh(float a, float b) {
    return (unsigned)f2h(a) | ((unsigned)f2h(b) << 16);
}
// packed f32->f16x2 convert (v_cvt_pkrtz_f16_f32), bit-cast to our h16x2
__device__ inline h16x2 pkrtz(float a, float b) {
    return __builtin_bit_cast(h16x2, __builtin_amdgcn_cvt_pkrtz(a, b));
}
// single-instruction lane xor-shuffles (BitMode ds_swizzle), within 32-lane groups
template <int MASK>
__device__ inline float swzx(float x) {
    constexpr int pat = (MASK << 10) | 0x1F;
    return __int_as_float(__builtin_amdgcn_ds_swizzle(__float_as_int(x), pat));
}
template <int MASK>
__device__ inline h16x2 swzh(h16x2 x) {
    constexpr int pat = (MASK << 10) | 0x1F;
    int t = __builtin_amdgcn_ds_swizzle(__builtin_bit_cast(int, x), pat);
    return __builtin_bit_cast(h16x2, t);
}
}

// ---------------------------------------------------------------------------
// W12 = Wout1 @ Wout2 (f32, [129][128]; row 128 = fused bias b12).
// ---------------------------------------------------------------------------
__global__ __launch_bounds__(256) void vsa_k_w12(
    const float* __restrict__ Wout1, const float* __restrict__ bout1,
    const float* __restrict__ Wout2, const float* __restrict__ bout2,
    float* __restrict__ w12)
{
    const int c = threadIdx.x & 127;
    const int k = blockIdx.x * 2 + (threadIdx.x >> 7);
    if (k > 128) return;
    const float* arow = (k < 128) ? (Wout1 + (size_t)k * 128) : bout1;
    float acc = (k < 128) ? 0.f : bout2[c];
    #pragma unroll 4
    for (int j = 0; j < 128; ++j)
        acc = fmaf(arow[j], Wout2[(size_t)j * 128 + c], acc);
    w12[(size_t)k * 128 + c] = acc;
}

// ---------------------------------------------------------------------------
// Prep: pack weights into MFMA fragment order wt[ks][f][lane][8 elems].
// wtp = bf16 (proj GEMM), wtp2 = f16 (out GEMM, from materialized w12).
// ---------------------------------------------------------------------------
__global__ __launch_bounds__(256) void vsa_k_prep(
    const float* __restrict__ Wv,    const float* __restrict__ bv,
    const float* __restrict__ Woff,  const float* __restrict__ boff,
    const float* __restrict__ Wattn, const float* __restrict__ battn,
    const float* __restrict__ w12,
    ushort* __restrict__ wtp, ushort* __restrict__ wtp2,
    float* __restrict__ biasp, float* __restrict__ bias2)
{
    const int u = blockIdx.x * 256 + threadIdx.x;
    constexpr int NP = KS * NF_P * 64;   // 3584
    constexpr int NO = KS * NF_O * 64;   // 2048

    if (u < NP) {
        int ks  = u / (NF_P * 64);
        int rem = u - ks * (NF_P * 64);
        int f = rem >> 6, l = rem & 63;
        int n  = f * 16 + (l & 15);
        int kb = ks * 32 + (l >> 4) * 8;
        float v[8];
        #pragma unroll
        for (int e = 0; e < 8; ++e) {
            int k = kb + e;
            if (n < 128)      v[e] = Wv[k * 128 + n];
            else if (n < 192) v[e] = Woff[k * 64 + (n - 128)];
            else              v[e] = Wattn[k * 32 + (n - 192)];
        }
        unsigned* dst = (unsigned*)(wtp + (size_t)u * 8);
        #pragma unroll
        for (int i = 0; i < 4; ++i) dst[i] = packbf(v[2*i], v[2*i+1]);
    } else if (u < NP + NO) {
        int t   = u - NP;
        int ks  = t / (NF_O * 64);
        int rem = t - ks * (NF_O * 64);
        int f = rem >> 6, l = rem & 63;
        int n  = f * 16 + (l & 15);
        int kb = ks * 32 + (l >> 4) * 8;
        unsigned* dst = (unsigned*)(wtp2 + (size_t)t * 8);
        #pragma unroll
        for (int i = 0; i < 4; ++i)
            dst[i] = packh(w12[(size_t)(kb + 2*i) * 128 + n],
                           w12[(size_t)(kb + 2*i + 1) * 128 + n]);
    } else if (u < NP + NO + 224) {
        int c = u - NP - NO;
        float bb;
        if (c < 128)      bb = bv[c];
        else if (c < 192) bb = boff[c - 128];
        else              bb = battn[c - 192];
        biasp[c] = bb;
    } else if (u < NP + NO + 224 + 128) {
        int c = u - NP - NO - 224;
        bias2[c] = w12[(size_t)128 * 128 + c];
    }
}

// ---------------------------------------------------------------------------
// Fused projection GEMM (MFMA, no LDS) + softmax epilogue.
//   cols 0..127   -> proj_v16 (f16 values)
//   cols 128..191 -> proj_s16[row][hp*4 + {0,1}] (f16 offsets)
//   cols 192..223 -> softmax over each 8-point group (lanes m&7 via xor
//                    ds_swizzle 1/2/4) -> proj_s16[row][hp*4 + 2] (f16 wp)
// ---------------------------------------------------------------------------
__global__ __launch_bounds__(256) void vsa_k_proj(
    const float* __restrict__ Q, const ushort* __restrict__ wtp,
    const float* __restrict__ biasp,
    ushort* __restrict__ proj_v16, ushort* __restrict__ proj_s16)
{
    const int lane = threadIdx.x & 63;
    const int wave = blockIdx.x * 4 + (threadIdx.x >> 6);
    const int row0 = wave * 16;
    const int m  = lane & 15;
    const int kg = lane >> 4;

    const float* qp = Q + (size_t)(row0 + m) * 128 + kg * 8;

    f32x4 acc[NF_P];
    #pragma unroll
    for (int f = 0; f < NF_P; ++f) acc[f] = (f32x4){0.f, 0.f, 0.f, 0.f};

    #pragma unroll
    for (int ks = 0; ks < KS; ++ks) {
        float4 a0 = *(const float4*)(qp + ks * 32);
        float4 a1 = *(const float4*)(qp + ks * 32 + 4);
        short8 af;
        af[0] = (short)f2bf(a0.x); af[1] = (short)f2bf(a0.y);
        af[2] = (short)f2bf(a0.z); af[3] = (short)f2bf(a0.w);
        af[4] = (short)f2bf(a1.x); af[5] = (short)f2bf(a1.y);
        af[6] = (short)f2bf(a1.z); af[7] = (short)f2bf(a1.w);
        const short8* wrow = (const short8*)wtp + ks * NF_P * 64 + lane;
        #pragma unroll
        for (int f = 0; f < NF_P; ++f)
            acc[f] = __builtin_amdgcn_mfma_f32_16x16x32_bf16(af, wrow[f * 64], acc[f], 0, 0, 0);
    }

    // values -> f16
    #pragma unroll
    for (int f = 0; f < 8; ++f) {
        const int col = f * 16 + m;
        const float bb = biasp[col];
        #pragma unroll
        for (int r = 0; r < 4; ++r)
            proj_v16[(size_t)(row0 + kg * 4 + r) * 128 + col] = f2h(acc[f][r] + bb);
    }
    // offsets -> f16 at [hp*4 + comp]
    #pragma unroll
    for (int f = 8; f < 12; ++f) {
        const int col = f * 16 + m;
        const float bb = biasp[col];
        const int c  = col - 128;          // 0..63
        const int hp = c >> 1, comp = c & 1;
        #pragma unroll
        for (int r = 0; r < 4; ++r)
            proj_s16[(size_t)(row0 + kg * 4 + r) * SC + hp * 4 + comp] = f2h(acc[f][r] + bb);
    }
    // attn logits -> softmax -> f16 weights at [hp*4 + 2]
    #pragma unroll
    for (int f = 12; f < 14; ++f) {
        const float bb = biasp[f * 16 + m];
        const int hp = (f - 12) * 16 + m;  // 0..31
        #pragma unroll
        for (int r = 0; r < 4; ++r) {
            float v = acc[f][r] + bb;
            float mx = v;
            mx = fmaxf(mx, swzx<1>(mx));
            mx = fmaxf(mx, swzx<2>(mx));
            mx = fmaxf(mx, swzx<4>(mx));
            float ex = __expf(v - mx);
            float sm = ex;
            sm += swzx<1>(sm); sm += swzx<2>(sm); sm += swzx<4>(sm);
            const float wp = ex / sm;
            proj_s16[(size_t)(row0 + kg * 4 + r) * SC + hp * 4 + 2] = f2h(wp);
        }
    }
}

// ---------------------------------------------------------------------------
// FUSED sampling + output GEMM, 16 waves/block (1024 threads): each wave
// runs only TWO sampling units (restores r10's proven per-wave parallelism;
// 80k waves) while keeping fusion's tmp-traffic savings. One block = 16
// consecutive bn rows. Sampling results -> LDS (f16, pad-136). Barrier.
// GEMM: waves 0..7 own one output fragment each; waves 8..15 exit.
// Nontemporal Q/out. XCD swizzle: 5000 blocks = 8 x 625.
// ---------------------------------------------------------------------------
__global__ __launch_bounds__(1024) void vsa_k_so(
    const ushort* __restrict__ proj_v16, const ushort* __restrict__ proj_s16,
    const ushort* __restrict__ wtp2, const float* __restrict__ bias2,
    const float* __restrict__ Q, float* __restrict__ out)
{
    __shared__ ushort tmp_lds[16][136];   // 16 rows x 128 f16, pad 8 (16B)

    const int lane = threadIdx.x & 63;
    const int wv   = threadIdx.x >> 6;     // wave 0..15
    const int hsub = lane >> 5;            // head within pair
    const int p    = (lane >> 2) & 7;      // point (bits 2..4)
    const int d8   = lane & 3;             // 8-value quad (bits 0..1)

    const int orig = blockIdx.x;                      // 0..4999
    const int wg   = (orig & 7) * 625 + (orig >> 3);  // bijective (5000%8==0)
    const int b    = wg / 2500;
    const int bl0  = (wg - b * 2500) * 16;            // bn_local0, 0..39984
    const int i0   = bl0 / 200;
    const int j0   = bl0 - i0 * 200;
    const int bn0  = b * N + bl0;

    const ushort* vb = proj_v16 + (size_t)b * N * 128;

    #pragma unroll
    for (int t = 0; t < 2; ++t) {
        const int unit = t * 16 + wv;       // 0..31
        const int pix  = unit >> 1;         // 0..15
        const int h    = (unit & 1) * 2 + hsub;
        const int jr   = j0 + pix;
        const bool wr  = jr >= 200;         // 16 consecutive bn may wrap one i
        const int i    = i0 + (wr ? 1 : 0);
        const int j    = wr ? jr - 200 : jr;
        const int bn   = bn0 + pix;

        // per-point data: one uint2 = {offx, offy, wp, pad} f16
        const uint2 ow = *(const uint2*)(proj_s16 + (size_t)bn * SC + (h * 8 + p) * 4);
        const float2 off = h2f2(ow.x);
        const float  wp  = h1f((ushort)(ow.y & 0xffff));

        const float ixf = (float)i + off.x;
        const float iyf = (float)j + off.y;
        const float x0f = floorf(ixf), y0f = floorf(iyf);
        const float lx = ixf - x0f, ly = iyf - y0f;
        const int x0 = (int)x0f, y0 = (int)y0f;
        const int x1 = x0 + 1,  y1 = y0 + 1;
        const int xc0 = min(max(x0, 0), X - 1), xc1 = min(max(x1, 0), X - 1);
        const int yc0 = min(max(y0, 0), Z - 1), yc1 = min(max(y1, 0), Z - 1);

        const float wx0 = ((unsigned)x0 < (unsigned)X) ? (1.f - lx) : 0.f;
        const float wx1 = ((unsigned)x1 < (unsigned)X) ? lx : 0.f;
        const float wy0 = (((unsigned)y0 < (unsigned)Z) ? (1.f - ly) : 0.f) * wp;
        const float wy1 = (((unsigned)y1 < (unsigned)Z) ? ly : 0.f) * wp;

        const h16x2 w00p = pkrtz(wx0 * wy0, wx0 * wy0);
        const h16x2 w10p = pkrtz(wx1 * wy0, wx1 * wy0);
        const h16x2 w01p = pkrtz(wx0 * wy1, wx0 * wy1);
        const h16x2 w11p = pkrtz(wx1 * wy1, wx1 * wy1);

        const int rb0 = yc0 * X, rb1 = yc1 * X;
        const int hb  = h * 32 + d8 * 8;    // f16-elem offset in 128-elem row

        const uint4 c00 = *(const uint4*)(vb + (size_t)(rb0 + xc0) * 128 + hb);
        const uint4 c10 = *(const uint4*)(vb + (size_t)(rb0 + xc1) * 128 + hb);
        const uint4 c01 = *(const uint4*)(vb + (size_t)(rb1 + xc0) * 128 + hb);
        const uint4 c11 = *(const uint4*)(vb + (size_t)(rb1 + xc1) * 128 + hb);

        h16x2 a0 = (h16x2)0, a1 = (h16x2)0, a2 = (h16x2)0, a3 = (h16x2)0;
        #define VSA_ACC(c, wpk) { \
            a0 = __builtin_elementwise_fma(__builtin_bit_cast(h16x2, (c).x), wpk, a0); \
            a1 = __builtin_elementwise_fma(__builtin_bit_cast(h16x2, (c).y), wpk, a1); \
            a2 = __builtin_elementwise_fma(__builtin_bit_cast(h16x2, (c).z), wpk, a2); \
            a3 = __builtin_elementwise_fma(__builtin_bit_cast(h16x2, (c).w), wpk, a3); }
        VSA_ACC(c00, w00p)
        VSA_ACC(c10, w10p)
        VSA_ACC(c01, w01p)
        VSA_ACC(c11, w11p)
        #undef VSA_ACC

        // reduce over the 8 points (p = lane bits 2..4), within 32 lanes
        a0 += swzh<4>(a0);  a1 += swzh<4>(a1);  a2 += swzh<4>(a2);  a3 += swzh<4>(a3);
        a0 += swzh<8>(a0);  a1 += swzh<8>(a1);  a2 += swzh<8>(a2);  a3 += swzh<8>(a3);
        a0 += swzh<16>(a0); a1 += swzh<16>(a1); a2 += swzh<16>(a2); a3 += swzh<16>(a3);

        if (p == 0) {   // lanes {0..3, 32..35}: one 16B LDS store per head
            uint4 o;
            o.x = __builtin_bit_cast(unsigned, a0);
            o.y = __builtin_bit_cast(unsigned, a1);
            o.z = __builtin_bit_cast(unsigned, a2);
            o.w = __builtin_bit_cast(unsigned, a3);
            *(uint4*)(&tmp_lds[pix][h * 32 + d8 * 8]) = o;
        }
    }

    // ---- prefetch Q residual (GEMM waves only; hides under barrier) ----
    const int m  = lane & 15;
    const int kg = lane >> 4;
    const int col = (wv & 7) * 16 + m;
    float qv[4];
    if (wv < 8) {
        #pragma unroll
        for (int r = 0; r < 4; ++r)
            qv[r] = __builtin_nontemporal_load(Q + (size_t)(bn0 + kg * 4 + r) * 128 + col);
    }

    __syncthreads();
    if (wv >= 8) return;

    // ---- output GEMM phase: wave wv owns fragment wv ----
    f32x4 acc = (f32x4){0.f, 0.f, 0.f, 0.f};
    #pragma unroll
    for (int ks = 0; ks < KS; ++ks) {
        short8 af = *(const short8*)(&tmp_lds[m][ks * 32 + kg * 8]);
        const short8* wrow = (const short8*)wtp2 + ks * NF_O * 64 + lane;
        acc = __builtin_amdgcn_mfma_f32_16x16x32_f16(af, wrow[wv * 64], acc, 0, 0, 0);
    }

    const float bb = bias2[col];
    #pragma unroll
    for (int r = 0; r < 4; ++r) {
        const size_t gi = (size_t)(bn0 + kg * 4 + r) * 128 + col;
        __builtin_nontemporal_store(acc[r] + bb + qv[r], out + gi);
    }
}

// ---------------------------------------------------------------------------
extern "C" void kernel_launch(void* const* d_in, const int* in_sizes, int n_in,
                              void* d_out, int out_size, void* d_ws, size_t ws_size,
                              hipStream_t stream) {
    const float* Q     = (const float*)d_in[0];
    const float* Wv    = (const float*)d_in[1];
    const float* bv    = (const float*)d_in[2];
    const float* Woff  = (const float*)d_in[3];
    const float* boff  = (const float*)d_in[4];
    const float* Wattn = (const float*)d_in[5];
    const float* battn = (const float*)d_in[6];
    const float* Wout1 = (const float*)d_in[7];
    const float* bout1 = (const float*)d_in[8];
    const float* Wout2 = (const float*)d_in[9];
    const float* bout2 = (const float*)d_in[10];
    float* out = (float*)d_out;

    // Workspace: biasp f32[224] | b12 f32[128] | w12 f32[129*128] |
    //            proj_s16 u16[BN][128] | proj_v16 u16[BN][128] | wtp | wtp2
    float*  biasp  = (float*)d_ws;
    float*  bias2  = biasp + 224;
    float*  w12    = bias2 + 128;
    ushort* proj_s16 = (ushort*)(w12 + 129 * 128);
    ushort* proj_v16 = proj_s16 + (size_t)BN * SC;
    ushort* wtp    = proj_v16 + (size_t)BN * 128;
    ushort* wtp2   = wtp + (size_t)KS * NF_P * 64 * 8;

    constexpr int prep_n = KS * NF_P * 64 + KS * NF_O * 64 + 224 + 128; // 5984
    vsa_k_w12<<<65, 256, 0, stream>>>(Wout1, bout1, Wout2, bout2, w12);
    vsa_k_prep<<<(prep_n + 255) / 256, 256, 0, stream>>>(
        Wv, bv, Woff, boff, Wattn, battn, w12, wtp, wtp2, biasp, bias2);
    vsa_k_proj<<<BN / 64, 256, 0, stream>>>(Q, wtp, biasp, proj_v16, proj_s16);
    vsa_k_so<<<BN / 16, 1024, 0, stream>>>(proj_v16, proj_s16, wtp2, bias2, Q, out);
}